// Round 4
// baseline (31.477 us; speedup 1.0000x reference)
//
#include <hip/hip_runtime.h>
#include <math.h>

// out_j = sum_{kk,ll < NF} P[ll,kk] cos(kk x_j) cos(ll y_j)
//                        + Q[ll,kk] sin(kk x_j) sin(ll y_j)
// NF=25 truncation of the exp(-0.02 f^2)-weighted folded 128x128 grid.
// PQ rows padded to 64 floats (P at +0, Q at +32) for aligned s_load bursts.
// The eval loop is software-pipelined at half-row granularity: Q_l loads
// while P_l computes; P_{l+1} loads while Q_l computes.

#define NF 25
#define RSTRIDE 64        // floats per l-row slot
#define NPQ (NF * NF)     // 625
#define BLOCK 256

__global__ void fold_pq(const float* __restrict__ coef, float* __restrict__ PQ)
{
    int t = blockIdx.x * blockDim.x + threadIdx.x;
    if (t >= NPQ) return;
    int ll = t / NF;
    int kk = t - ll * NF;
    float Pv = 0.f, Qv = 0.f;
    int   iv[2]; float isg[2]; int ni;
    iv[0] = 64 - kk; isg[0] = (kk == 0) ? 0.f : -1.f; ni = 1;
    if (kk >= 1) { iv[1] = 64 + kk; isg[1] = 1.f; ni = 2; }
    int   jv[2]; float jsg[2]; int nj;
    jv[0] = 64 - ll; jsg[0] = (ll == 0) ? 0.f : -1.f; nj = 1;
    if (ll >= 1) { jv[1] = 64 + ll; jsg[1] = 1.f; nj = 2; }
    for (int a = 0; a < ni; ++a) {
        for (int b = 0; b < nj; ++b) {
            int i = iv[a], j = jv[b];
            float fx = (float)(i - 64), fy = (float)(j - 64);
            float w  = expf(-0.02f * (fx * fx + fy * fy));
            float cw = coef[(i << 7) + j] * w;
            Pv += cw;
            Qv -= isg[a] * jsg[b] * cw;
        }
    }
    PQ[ll * RSTRIDE + kk]      = Pv;
    PQ[ll * RSTRIDE + 32 + kk] = Qv;
}

__global__ __launch_bounds__(BLOCK, 4)
void fouriergp_eval(const float* __restrict__ PQ,
                    const float* __restrict__ xs,
                    const float* __restrict__ ys,
                    float* __restrict__ out, int M)
{
    int jidx = blockIdx.x * BLOCK + threadIdx.x;
    if (jidx >= M) return;
    float xj = xs[jidx], yj = ys[jidx];

    float c1, s1;   sincosf(xj, &s1, &c1);
    float cy1, sy1; sincosf(yj, &sy1, &cy1);

    // Trig tables cos(k x), sin(k x), k=0..NF-1 (rotation recurrence, VGPRs).
    float cx[NF], sx[NF];
    cx[0] = 1.f; sx[0] = 0.f;
    cx[1] = c1;  sx[1] = s1;
    #pragma unroll
    for (int k = 2; k < NF; ++k) {
        cx[k] = cx[k - 1] * c1 - sx[k - 1] * s1;
        sx[k] = sx[k - 1] * c1 + cx[k - 1] * s1;
    }

    // Software-pipelined main loop. pbuf/qbuf hold wave-uniform row halves
    // (fully-unrolled indices -> SSA -> SGPRs via s_load).
    float pbuf[NF], qbuf[NF];
    #pragma unroll
    for (int k = 0; k < NF; ++k) pbuf[k] = PQ[k];           // prologue: P row 0

    float acc = 0.f, cyl = 1.f, syl = 0.f;
    #pragma unroll 1
    for (int l = 0; l < NF; ++l) {
        const float* __restrict__ rq = PQ + l * RSTRIDE + 32;
        #pragma unroll
        for (int k = 0; k < NF; ++k) qbuf[k] = rq[k];       // issue Q_l loads

        float a0 = 0.f, a1 = 0.f, a2 = 0.f, a3 = 0.f;       // compute P_l
        #pragma unroll
        for (int k = 0; k < NF - 1; k += 4) {
            a0 = fmaf(pbuf[k],     cx[k],     a0);
            a1 = fmaf(pbuf[k + 1], cx[k + 1], a1);
            a2 = fmaf(pbuf[k + 2], cx[k + 2], a2);
            a3 = fmaf(pbuf[k + 3], cx[k + 3], a3);
        }
        a0 = fmaf(pbuf[NF - 1], cx[NF - 1], a0);
        acc = fmaf((a0 + a1) + (a2 + a3), cyl, acc);

        const float* __restrict__ rp = PQ + (l + 1) * RSTRIDE;
        #pragma unroll
        for (int k = 0; k < NF; ++k) pbuf[k] = rp[k];       // issue P_{l+1} loads
        // (last iteration prefetches an unused garbage row inside d_ws)

        float b0 = 0.f, b1 = 0.f, b2 = 0.f, b3 = 0.f;       // compute Q_l
        #pragma unroll
        for (int k = 0; k < NF - 1; k += 4) {
            b0 = fmaf(qbuf[k],     sx[k],     b0);
            b1 = fmaf(qbuf[k + 1], sx[k + 1], b1);
            b2 = fmaf(qbuf[k + 2], sx[k + 2], b2);
            b3 = fmaf(qbuf[k + 3], sx[k + 3], b3);
        }
        b0 = fmaf(qbuf[NF - 1], sx[NF - 1], b0);
        acc = fmaf((b0 + b1) + (b2 + b3), syl, acc);

        float cn = fmaf(cyl, cy1, -syl * sy1);              // advance y-rotation
        float sn = fmaf(syl, cy1,  cyl * sy1);
        cyl = cn; syl = sn;
    }
    out[jidx] = acc;
}

extern "C" void kernel_launch(void* const* d_in, const int* in_sizes, int n_in,
                              void* d_out, int out_size, void* d_ws, size_t ws_size,
                              hipStream_t stream) {
    const float* coef = (const float*)d_in[0];
    const float* x    = (const float*)d_in[1];
    const float* y    = (const float*)d_in[2];
    float* out = (float*)d_out;
    float* PQ  = (float*)d_ws;
    int M = in_sizes[1];

    fold_pq<<<(NPQ + BLOCK - 1) / BLOCK, BLOCK, 0, stream>>>(coef, PQ);
    fouriergp_eval<<<(M + BLOCK - 1) / BLOCK, BLOCK, 0, stream>>>(PQ, x, y, out, M);
}

// Round 5
// 28.843 us; speedup vs baseline: 1.0913x; 1.0913x over previous
//
#include <hip/hip_runtime.h>
#include <math.h>

// out_j = sum_{kk,ll < NF} P[ll,kk] cos(kk x_j) cos(ll y_j)
//                        + Q[ll,kk] sin(kk x_j) sin(ll y_j)
// NF=24 truncation of the exp(-0.02 f^2)-weighted folded 128x128 grid
// (weight < 1e-5 for f>=24; truncation error ~1e-3 vs 0.41 threshold).
// PQ rows are 48 contiguous floats [P row | Q row]. Row offsets are forced
// through readfirstlane so the row loads select s_load (SMEM pipe, no TA
// serialization). Half-row ping-pong hides the forced lgkmcnt(0) drains
// under ~24 FMAs of compute per half-row.

#define NF 24
#define ROW (2 * NF)       // 48 floats per l-row
#define NPQ (NF * NF)      // 576
#define BLOCK 256

__global__ void fold_pq(const float* __restrict__ coef, float* __restrict__ PQ)
{
    int t = blockIdx.x * blockDim.x + threadIdx.x;
    if (t >= NPQ) return;
    int ll = t / NF;
    int kk = t - ll * NF;
    float Pv = 0.f, Qv = 0.f;
    int   iv[2]; float isg[2]; int ni;
    iv[0] = 64 - kk; isg[0] = (kk == 0) ? 0.f : -1.f; ni = 1;
    if (kk >= 1) { iv[1] = 64 + kk; isg[1] = 1.f; ni = 2; }
    int   jv[2]; float jsg[2]; int nj;
    jv[0] = 64 - ll; jsg[0] = (ll == 0) ? 0.f : -1.f; nj = 1;
    if (ll >= 1) { jv[1] = 64 + ll; jsg[1] = 1.f; nj = 2; }
    for (int a = 0; a < ni; ++a) {
        for (int b = 0; b < nj; ++b) {
            int i = iv[a], j = jv[b];
            float fx = (float)(i - 64), fy = (float)(j - 64);
            float w  = expf(-0.02f * (fx * fx + fy * fy));
            float cw = coef[(i << 7) + j] * w;
            Pv += cw;
            Qv -= isg[a] * jsg[b] * cw;
        }
    }
    PQ[ll * ROW + kk]      = Pv;
    PQ[ll * ROW + NF + kk] = Qv;
}

__global__ __launch_bounds__(BLOCK, 4)
void fouriergp_eval(const float* __restrict__ PQ,
                    const float* __restrict__ xs,
                    const float* __restrict__ ys,
                    float* __restrict__ out, int M)
{
    int jidx = blockIdx.x * BLOCK + threadIdx.x;
    if (jidx >= M) jidx = M - 1;   // branch-free clamp: CFG stays uniform
    float xj = xs[jidx], yj = ys[jidx];

    float c1, s1;   sincosf(xj, &s1, &c1);
    float cy1, sy1; sincosf(yj, &sy1, &cy1);

    // Trig tables cos(k x), sin(k x), k=0..NF-1 (rotation recurrence, VGPRs).
    float cx[NF], sx[NF];
    cx[0] = 1.f; sx[0] = 0.f;
    cx[1] = c1;  sx[1] = s1;
    #pragma unroll
    for (int k = 2; k < NF; ++k) {
        cx[k] = cx[k - 1] * c1 - sx[k - 1] * s1;
        sx[k] = sx[k - 1] * c1 + cx[k - 1] * s1;
    }

    // Ping-pong half-row buffers; wave-uniform addresses forced to SGPR.
    float pbuf[NF], qbuf[NF];
    {
        const float* __restrict__ r0 = PQ + __builtin_amdgcn_readfirstlane(0);
        #pragma unroll
        for (int k = 0; k < NF; ++k) pbuf[k] = r0[k];       // P row 0
    }

    float acc = 0.f, cyl = 1.f, syl = 0.f;
    #pragma unroll 1
    for (int l = 0; l < NF; ++l) {
        const float* __restrict__ rq =
            PQ + __builtin_amdgcn_readfirstlane(l * ROW + NF);
        #pragma unroll
        for (int k = 0; k < NF; ++k) qbuf[k] = rq[k];       // issue Q_l

        float a0 = 0.f, a1 = 0.f, a2 = 0.f, a3 = 0.f;       // compute P_l
        #pragma unroll
        for (int k = 0; k < NF; k += 4) {
            a0 = fmaf(pbuf[k],     cx[k],     a0);
            a1 = fmaf(pbuf[k + 1], cx[k + 1], a1);
            a2 = fmaf(pbuf[k + 2], cx[k + 2], a2);
            a3 = fmaf(pbuf[k + 3], cx[k + 3], a3);
        }
        acc = fmaf((a0 + a1) + (a2 + a3), cyl, acc);

        const float* __restrict__ rp =
            PQ + __builtin_amdgcn_readfirstlane((l + 1) * ROW);
        #pragma unroll
        for (int k = 0; k < NF; ++k) pbuf[k] = rp[k];       // issue P_{l+1}
        // (last iteration prefetches an unused row inside d_ws)

        float b0 = 0.f, b1 = 0.f, b2 = 0.f, b3 = 0.f;       // compute Q_l
        #pragma unroll
        for (int k = 0; k < NF; k += 4) {
            b0 = fmaf(qbuf[k],     sx[k],     b0);
            b1 = fmaf(qbuf[k + 1], sx[k + 1], b1);
            b2 = fmaf(qbuf[k + 2], sx[k + 2], b2);
            b3 = fmaf(qbuf[k + 3], sx[k + 3], b3);
        }
        acc = fmaf((b0 + b1) + (b2 + b3), syl, acc);

        float cn = fmaf(cyl, cy1, -syl * sy1);              // advance y-rotation
        float sn = fmaf(syl, cy1,  cyl * sy1);
        cyl = cn; syl = sn;
    }
    out[jidx] = acc;
}

extern "C" void kernel_launch(void* const* d_in, const int* in_sizes, int n_in,
                              void* d_out, int out_size, void* d_ws, size_t ws_size,
                              hipStream_t stream) {
    const float* coef = (const float*)d_in[0];
    const float* x    = (const float*)d_in[1];
    const float* y    = (const float*)d_in[2];
    float* out = (float*)d_out;
    float* PQ  = (float*)d_ws;
    int M = in_sizes[1];

    fold_pq<<<(NPQ + BLOCK - 1) / BLOCK, BLOCK, 0, stream>>>(coef, PQ);
    fouriergp_eval<<<(M + BLOCK - 1) / BLOCK, BLOCK, 0, stream>>>(PQ, x, y, out, M);
}

// Round 6
// 25.612 us; speedup vs baseline: 1.2290x; 1.1262x over previous
//
#include <hip/hip_runtime.h>
#include <math.h>

// out_j = sum_{kk,ll < NF} P[ll,kk] cos(kk x_j) cos(ll y_j)
//                        + Q[ll,kk] sin(kk x_j) sin(ll y_j)
// NF=24 truncation of the exp(-0.02 f^2)-weighted folded 128x128 grid.
// PQ rows are 256 B slots: P half at +0 (24 floats), Q half at +128 B.
// Coefficient rows are loaded with explicit s_load_dwordx16/x8 into SGPRs
// (inline asm) so the broadcast operand never touches the TA/L1 vector
// path; v_fmac_f32 reads the coefficient straight from the SGPR.

#define NF 24
#define RSTR 64            // floats per row slot (256 B)
#define NPQ (NF * NF)
#define BLOCK 256

typedef int v16i __attribute__((ext_vector_type(16)));
typedef int v8i  __attribute__((ext_vector_type(8)));

// load 24 floats (96 B) at 64B-aligned ptr into s-tuples
#define SLOAD_HALF(d16, d8, ptr)                                   \
    asm volatile("s_load_dwordx16 %0, %2, 0\n\t"                   \
                 "s_load_dwordx8  %1, %2, 64"                      \
                 : "=&s"(d16), "=&s"(d8) : "s"(ptr))

// drain SMEM; dataflow through the tuples orders uses after the wait
#define SWAIT(d16, d8)                                             \
    asm volatile("s_waitcnt lgkmcnt(0)" : "+s"(d16), "+s"(d8))

__device__ __forceinline__ float elt(const v16i& a, const v8i& b, int k) {
    return __int_as_float(k < 16 ? a[k] : b[k - 16]);
}

__global__ void fold_pq(const float* __restrict__ coef, float* __restrict__ PQ)
{
    int t = blockIdx.x * blockDim.x + threadIdx.x;
    if (t >= NPQ) return;
    int ll = t / NF;
    int kk = t - ll * NF;
    float Pv = 0.f, Qv = 0.f;
    int   iv[2]; float isg[2]; int ni;
    iv[0] = 64 - kk; isg[0] = (kk == 0) ? 0.f : -1.f; ni = 1;
    if (kk >= 1) { iv[1] = 64 + kk; isg[1] = 1.f; ni = 2; }
    int   jv[2]; float jsg[2]; int nj;
    jv[0] = 64 - ll; jsg[0] = (ll == 0) ? 0.f : -1.f; nj = 1;
    if (ll >= 1) { jv[1] = 64 + ll; jsg[1] = 1.f; nj = 2; }
    for (int a = 0; a < ni; ++a) {
        for (int b = 0; b < nj; ++b) {
            int i = iv[a], j = jv[b];
            float fx = (float)(i - 64), fy = (float)(j - 64);
            float w  = expf(-0.02f * (fx * fx + fy * fy));
            float cw = coef[(i << 7) + j] * w;
            Pv += cw;
            Qv -= isg[a] * jsg[b] * cw;
        }
    }
    PQ[ll * RSTR + kk]      = Pv;
    PQ[ll * RSTR + 32 + kk] = Qv;
}

__global__ __launch_bounds__(BLOCK, 4)
void fouriergp_eval(const float* __restrict__ PQ,
                    const float* __restrict__ xs,
                    const float* __restrict__ ys,
                    float* __restrict__ out, int M)
{
    int jidx = blockIdx.x * BLOCK + threadIdx.x;
    if (jidx >= M) jidx = M - 1;   // branch-free clamp (grid is exact anyway)
    float xj = xs[jidx], yj = ys[jidx];

    float c1, s1;   sincosf(xj, &s1, &c1);
    float cy1, sy1; sincosf(yj, &sy1, &cy1);

    // Trig tables cos(k x), sin(k x), k=0..NF-1 (rotation recurrence, VGPRs).
    float cx[NF], sx[NF];
    cx[0] = 1.f; sx[0] = 0.f;
    cx[1] = c1;  sx[1] = s1;
    #pragma unroll
    for (int k = 2; k < NF; ++k) {
        cx[k] = cx[k - 1] * c1 - sx[k - 1] * s1;
        sx[k] = sx[k - 1] * c1 + cx[k - 1] * s1;
    }

    v16i p0; v8i p1;   // P half-row in SGPRs
    v16i q0; v8i q1;   // Q half-row in SGPRs

    SLOAD_HALF(p0, p1, PQ);        // prologue: P row 0
    SWAIT(p0, p1);

    float acc = 0.f, cyl = 1.f, syl = 0.f;
    #pragma unroll 1
    for (int l = 0; l < NF; ++l) {
        const float* rq = PQ + l * RSTR + 32;
        SLOAD_HALF(q0, q1, rq);                      // issue Q_l

        float a0 = 0.f, a1 = 0.f, a2 = 0.f, a3 = 0.f;  // compute P_l
        #pragma unroll
        for (int k = 0; k < NF; k += 4) {
            a0 = fmaf(elt(p0, p1, k),     cx[k],     a0);
            a1 = fmaf(elt(p0, p1, k + 1), cx[k + 1], a1);
            a2 = fmaf(elt(p0, p1, k + 2), cx[k + 2], a2);
            a3 = fmaf(elt(p0, p1, k + 3), cx[k + 3], a3);
        }
        acc = fmaf((a0 + a1) + (a2 + a3), cyl, acc);

        SWAIT(q0, q1);                               // drain Q_l

        const float* rp = PQ + (l + 1) * RSTR;
        SLOAD_HALF(p0, p1, rp);                      // issue P_{l+1}
        // (last iteration prefetches an unused slot inside d_ws)

        float b0 = 0.f, b1 = 0.f, b2 = 0.f, b3 = 0.f;  // compute Q_l
        #pragma unroll
        for (int k = 0; k < NF; k += 4) {
            b0 = fmaf(elt(q0, q1, k),     sx[k],     b0);
            b1 = fmaf(elt(q0, q1, k + 1), sx[k + 1], b1);
            b2 = fmaf(elt(q0, q1, k + 2), sx[k + 2], b2);
            b3 = fmaf(elt(q0, q1, k + 3), sx[k + 3], b3);
        }
        acc = fmaf((b0 + b1) + (b2 + b3), syl, acc);

        SWAIT(p0, p1);                               // drain P_{l+1}

        float cn = fmaf(cyl, cy1, -syl * sy1);       // advance y-rotation
        float sn = fmaf(syl, cy1,  cyl * sy1);
        cyl = cn; syl = sn;
    }
    out[jidx] = acc;
}

extern "C" void kernel_launch(void* const* d_in, const int* in_sizes, int n_in,
                              void* d_out, int out_size, void* d_ws, size_t ws_size,
                              hipStream_t stream) {
    const float* coef = (const float*)d_in[0];
    const float* x    = (const float*)d_in[1];
    const float* y    = (const float*)d_in[2];
    float* out = (float*)d_out;
    float* PQ  = (float*)d_ws;
    int M = in_sizes[1];

    fold_pq<<<(NPQ + BLOCK - 1) / BLOCK, BLOCK, 0, stream>>>(coef, PQ);
    fouriergp_eval<<<(M + BLOCK - 1) / BLOCK, BLOCK, 0, stream>>>(PQ, x, y, out, M);
}